// Round 13
// baseline (530.993 us; speedup 1.0000x reference)
//
#include <hip/hip_runtime.h>
#include <math.h>

#define H        2048
#define HD       12288      // (NG+1)*H
#define DICT     50000
#define FDIM     6
#define RDIM     1
#define IN_DIM   16
#define EPS_F    1e-8f

// d_out flat offsets (floats), in reference return order
#define OFF_PI   ((size_t)0)
#define OFF_V    ((size_t)8)
#define OFF_H    ((size_t)9)
#define OFF_C    ((size_t)2057)
#define OFF_FK   ((size_t)4105)
#define OFF_FV   ((size_t)304105)    // ≡ 1 (mod 4): row-local float 4k+3 is 16B-aligned
#define OFF_RK   ((size_t)102704105)
#define OFF_RV   ((size_t)102754105) // ≡ 1 (mod 4), same phase

#define NBLK_SWEEP  800
#define NTH         (NBLK_SWEEP * 512)           // 409600 threads (all co-resident: 25 waves/CU)
#define PH_FLOATS   ((long long)DICT * H)        // 102 400 000 floats per dict
#define QPH         ((PH_FLOATS - 4) / 4)        // 25 599 999 aligned dst quads (at 4k+3)

typedef float f4v  __attribute__((ext_vector_type(4)));
typedef f4v  f4vu  __attribute__((aligned(4)));  // 4B-aligned vector load (single dwordx4)

__device__ __forceinline__ float sigf(float v) { return 1.0f / (1.0f + expf(-v)); }

// ---------------- zero scratch accumulators ----------------
__global__ void k_zero(float* __restrict__ p, int n) {
    int i = blockIdx.x * 256 + threadIdx.x;
    if (i < n) p[i] = 0.0f;
}

// ---------------- grid-wide DND exp-sims + keys copy + atomic sums ----------------
// |cos sim| <= 1 so softmax needs no max shift; 1/sum applied in k_combine.
__global__ __launch_bounds__(256) void k_sims(
    const float* __restrict__ f_keys, const float* __restrict__ r_keys,
    const float* __restrict__ x,
    float* __restrict__ ef, float* __restrict__ er,
    float* __restrict__ sums,
    float* __restrict__ out_fk, float* __restrict__ out_rk)
{
    __shared__ float red[4];
    const int i    = blockIdx.x * 256 + threadIdx.x;
    const int dict = blockIdx.y;
    float e = 0.0f;

    if (dict == 0) {
        float qn[FDIM]; float qs = 0.0f;
#pragma unroll
        for (int d = 0; d < FDIM; ++d) { float q = x[d]; qn[d] = q; qs += q * q; }
        float qi = 1.0f / (sqrtf(qs) + EPS_F);
        if (i < DICT) {
            float ks = 0.0f, dot = 0.0f;
#pragma unroll
            for (int d = 0; d < FDIM; ++d) {
                float kv = f_keys[(size_t)i * FDIM + d];
                out_fk[(size_t)i * FDIM + d] = kv;      // fused keys output copy
                ks += kv * kv; dot += kv * qn[d];
            }
            e = expf((dot * qi) / (sqrtf(ks) + EPS_F));
            ef[i] = e;
        }
    } else {
        float q  = x[FDIM];
        float qn = q / (fabsf(q) + EPS_F);
        if (i < DICT) {
            float kv = r_keys[i];
            out_rk[i] = kv;                              // fused keys output copy
            e = expf((kv * qn) / (fabsf(kv) + EPS_F));
            er[i] = e;
        }
    }
#pragma unroll
    for (int off = 32; off > 0; off >>= 1) e += __shfl_down(e, off);
    if ((threadIdx.x & 63) == 0) red[threadIdx.x >> 6] = e;
    __syncthreads();
    if (threadIdx.x == 0)
        atomicAdd(&sums[dict], red[0] + red[1] + red[2] + red[3]);
}

// ---------------- preact[r] = W_i2h[r,:]@x + W_h2h[r,:]@h + b  (wave per row) ----------------
__global__ __launch_bounds__(256) void k_preact(
    const float* __restrict__ W_h2h, const float* __restrict__ W_i2h,
    const float* __restrict__ b_h2h, const float* __restrict__ b_i2h,
    const float* __restrict__ h, const float* __restrict__ x,
    float* __restrict__ preact)
{
    int gid  = blockIdx.x * blockDim.x + threadIdx.x;
    int row  = gid >> 6;
    int lane = threadIdx.x & 63;
    if (row >= HD) return;
    const float4* Wv = (const float4*)(W_h2h + (size_t)row * H);
    const float4* hv = (const float4*)h;
    float acc = 0.0f;
#pragma unroll
    for (int k = 0; k < 8; ++k) {
        float4 w4 = Wv[lane + (k << 6)];
        float4 h4 = hv[lane + (k << 6)];
        acc += w4.x * h4.x + w4.y * h4.y + w4.z * h4.z + w4.w * h4.w;
    }
    if (lane < IN_DIM) acc += W_i2h[(size_t)row * IN_DIM + lane] * x[lane];
#pragma unroll
    for (int off = 32; off > 0; off >>= 1) acc += __shfl_down(acc, off);
    if (lane == 0) preact[row] = acc + b_h2h[row] + b_i2h[row];
}

// ---------------- flat sweep, DEPTH-4: copy one dict + weighted sum ----------------
// Thread g owns dst-aligned quads at row-local flat float 4k+3, k = g, g+NTH, ...
// Stride NTH quads = exactly 800 rows -> per-thread column set is FIXED.
// Depth-4 batch: 4 loads in flight, then 4 stores -> store-ack latency no longer
// serializes the loop (r10's defect). No barriers (r10 proved no write amplification).
__device__ __forceinline__ void sweep_phase(
    const float* __restrict__ src, float* __restrict__ dst,
    const float* __restrict__ w, float* __restrict__ mem, int g)
{
    const long long f0 = 4LL * g + 3;
    const int  c0 = (int)(f0 & 2047);            // fixed per thread
    int        r  = (int)(f0 >> 11);             // advances by 800 per step
    long long  fo = f0;
    long long  k  = g;
    float a0 = 0.f, a1 = 0.f, a2 = 0.f, a3 = 0.f;

    if (c0 != 2047) {                            // quad entirely within row (the 511/512 case)
#pragma unroll 1
        for (; k + 3LL * NTH < QPH; k += 4LL * NTH) {
            const float* s = src + fo;
            f4vu v0 = *(const f4vu*)(s);
            f4vu v1 = *(const f4vu*)(s + 4LL * NTH);
            f4vu v2 = *(const f4vu*)(s + 8LL * NTH);
            f4vu v3 = *(const f4vu*)(s + 12LL * NTH);
            const float w0 = w[r], w1 = w[r + 800], w2 = w[r + 1600], w3 = w[r + 2400];
            a0 += w0 * v0.x + w1 * v1.x + w2 * v2.x + w3 * v3.x;
            a1 += w0 * v0.y + w1 * v1.y + w2 * v2.y + w3 * v3.y;
            a2 += w0 * v0.z + w1 * v1.z + w2 * v2.z + w3 * v3.z;
            a3 += w0 * v0.w + w1 * v1.w + w2 * v2.w + w3 * v3.w;
            float* d = dst + fo;
            *(f4v*)(d)             = v0;
            *(f4v*)(d + 4LL * NTH) = v1;
            *(f4v*)(d + 8LL * NTH) = v2;
            *(f4v*)(d + 12LL * NTH) = v3;
            fo += 16LL * NTH; r += 4 * NBLK_SWEEP;
        }
#pragma unroll 1
        for (; k < QPH; k += NTH, fo += 4LL * NTH, r += NBLK_SWEEP) {
            f4vu v = *(const f4vu*)(src + fo);
            const float wr = w[r];
            a0 += wr * v.x; a1 += wr * v.y; a2 += wr * v.z; a3 += wr * v.w;
            *(f4v*)(dst + fo) = v;
        }
        atomicAdd(&mem[c0 + 0], a0);
        atomicAdd(&mem[c0 + 1], a1);
        atomicAdd(&mem[c0 + 2], a2);
        atomicAdd(&mem[c0 + 3], a3);
    } else {                                     // quad spans rows r | r+1 (cols 2047,0,1,2)
#pragma unroll 1
        for (; k < QPH; k += NTH, fo += 4LL * NTH, r += NBLK_SWEEP) {
            f4vu v = *(const f4vu*)(src + fo);
            const float wr = w[r], wn = w[r + 1];
            a0 += wr * v.x; a1 += wn * v.y; a2 += wn * v.z; a3 += wn * v.w;
            *(f4v*)(dst + fo) = v;
        }
        atomicAdd(&mem[2047], a0);
        atomicAdd(&mem[0],    a1);
        atomicAdd(&mem[1],    a2);
        atomicAdd(&mem[2],    a3);
    }
    if (g == 0) {                                // leftovers: head {0,1,2}, tail {last}
        float s0 = src[0], s1 = src[1], s2 = src[2], sl = src[PH_FLOATS - 1];
        dst[0] = s0; dst[1] = s1; dst[2] = s2; dst[PH_FLOATS - 1] = sl;
        const float w0 = w[0], wl = w[DICT - 1];
        atomicAdd(&mem[0],    w0 * s0);
        atomicAdd(&mem[1],    w0 * s1);
        atomicAdd(&mem[2],    w0 * s2);
        atomicAdd(&mem[2047], wl * sl);
    }
}

__global__ __launch_bounds__(512, 8) void k_sweep(
    const float* __restrict__ f_vals, const float* __restrict__ r_vals,
    const float* __restrict__ ef, const float* __restrict__ er,
    float* __restrict__ out_fv, float* __restrict__ out_rv,
    float* __restrict__ memfun, float* __restrict__ memrul)
{
    const int g = blockIdx.x * 512 + threadIdx.x;
    sweep_phase(f_vals, out_fv, ef, memfun, g);
    sweep_phase(r_vals, out_rv, er, memrul, g);
}

// ---------------- gates -> c_t, h_t; write h/c outputs + write_idx rows ----------------
__global__ __launch_bounds__(256) void k_combine(
    const float* __restrict__ preact, const float* __restrict__ c_in,
    const float* __restrict__ memfun, const float* __restrict__ memrul,
    const float* __restrict__ sums,
    const float* __restrict__ x, const int* __restrict__ widx_p,
    float* __restrict__ out, float* __restrict__ ht_ws)
{
    const int j = blockIdx.x * 256 + threadIdx.x;
    if (j >= H) return;
    const int widx = *widx_p;
    const float invf = 1.0f / sums[0];
    const float invr = 1.0f / sums[1];

    float f_t   = sigf(preact[0 * H + j]);
    float i_t   = sigf(preact[1 * H + j]);
    float o_t   = sigf(preact[2 * H + j]);
    float fun_t = sigf(preact[3 * H + j]);
    float rul_t = sigf(preact[4 * H + j]);
    float c_new = tanhf(preact[5 * H + j]);

    float ct = f_t * c_in[j] + i_t * c_new
             + fun_t * tanhf(memfun[j] * invf) + rul_t * tanhf(memrul[j] * invr);
    float ht = o_t * tanhf(ct);

    out[OFF_H + j] = ht;
    out[OFF_C + j] = ct;
    ht_ws[j] = ht;

    out[OFF_FV + (size_t)widx * H + j] = (j < H / 2) ? ct : 0.0f;
    out[OFF_RV + (size_t)widx * H + j] = (j < H / 2) ? 0.0f : ct;
    if (j < FDIM)  out[OFF_FK + (size_t)widx * FDIM + j] = x[j];
    if (j == FDIM) out[OFF_RK + (size_t)widx] = x[FDIM];
}

// ---------------- ha = relu(W_ih @ h_t + b_ih)  (wave per row) ----------------
__global__ __launch_bounds__(256) void k_hidden(
    const float* __restrict__ W_ih, const float* __restrict__ b_ih,
    const float* __restrict__ ht, float* __restrict__ ha)
{
    int gid  = blockIdx.x * blockDim.x + threadIdx.x;
    int row  = gid >> 6;
    int lane = threadIdx.x & 63;
    if (row >= H) return;
    const float4* Wv = (const float4*)(W_ih + (size_t)row * H);
    const float4* hv = (const float4*)ht;
    float acc = 0.0f;
#pragma unroll
    for (int k = 0; k < 8; ++k) {
        float4 w4 = Wv[lane + (k << 6)];
        float4 h4 = hv[lane + (k << 6)];
        acc += w4.x * h4.x + w4.y * h4.y + w4.z * h4.z + w4.w * h4.w;
    }
#pragma unroll
    for (int off = 32; off > 0; off >>= 1) acc += __shfl_down(acc, off);
    if (lane == 0) ha[row] = fmaxf(acc + b_ih[row], 0.0f);
}

// ---------------- heads stage 1: 9 parallel logit GEMVs ----------------
__global__ __launch_bounds__(256) void k_heads1(
    const float* __restrict__ W_actor, const float* __restrict__ b_actor,
    const float* __restrict__ W_critic, const float* __restrict__ b_critic,
    const float* __restrict__ ha, float* __restrict__ logits)
{
    __shared__ float red[4];
    const int o   = blockIdx.x;           // 0..8
    const int tid = threadIdx.x;
    const float* row = (o < 8) ? (W_actor + (size_t)o * H) : W_critic;
    const float4* rv = (const float4*)row;
    const float4* hv = (const float4*)ha;
    float acc = 0.0f;
#pragma unroll
    for (int k = 0; k < 2; ++k) {
        int idx = tid + (k << 8);
        float4 w4 = rv[idx];
        float4 h4 = hv[idx];
        acc += w4.x * h4.x + w4.y * h4.y + w4.z * h4.z + w4.w * h4.w;
    }
#pragma unroll
    for (int off = 32; off > 0; off >>= 1) acc += __shfl_down(acc, off);
    if ((tid & 63) == 0) red[tid >> 6] = acc;
    __syncthreads();
    if (tid == 0)
        logits[o] = red[0] + red[1] + red[2] + red[3] + ((o < 8) ? b_actor[o] : b_critic[0]);
}

// ---------------- heads stage 2: softmax over 8 + critic ----------------
__global__ __launch_bounds__(64) void k_heads2(
    const float* __restrict__ logits, float* __restrict__ out)
{
    if (threadIdx.x == 0) {
        float m = logits[0];
        for (int o = 1; o < 8; ++o) m = fmaxf(m, logits[o]);
        float e[8], s = 0.0f;
        for (int o = 0; o < 8; ++o) { e[o] = expf(logits[o] - m); s += e[o]; }
        for (int o = 0; o < 8; ++o) out[OFF_PI + o] = e[o] / s;
        out[OFF_V] = logits[8];
    }
}

extern "C" void kernel_launch(void* const* d_in, const int* in_sizes, int n_in,
                              void* d_out, int out_size, void* d_ws, size_t ws_size,
                              hipStream_t stream)
{
    const float* x        = (const float*)d_in[0];
    const float* h        = (const float*)d_in[1];
    const float* c        = (const float*)d_in[2];
    const float* W_i2h    = (const float*)d_in[3];
    const float* b_i2h    = (const float*)d_in[4];
    const float* W_h2h    = (const float*)d_in[5];
    const float* b_h2h    = (const float*)d_in[6];
    const float* f_keys   = (const float*)d_in[7];
    const float* f_vals   = (const float*)d_in[8];
    const float* r_keys   = (const float*)d_in[9];
    const float* r_vals   = (const float*)d_in[10];
    const float* W_ih     = (const float*)d_in[11];
    const float* b_ih     = (const float*)d_in[12];
    const float* W_actor  = (const float*)d_in[13];
    const float* b_actor  = (const float*)d_in[14];
    const float* W_critic = (const float*)d_in[15];
    const float* b_critic = (const float*)d_in[16];
    const int*   widx     = (const int*)d_in[17];

    float* out = (float*)d_out;
    float* ws  = (float*)d_ws;

    // ws layout (floats)
    float* preact = ws;                 // 12288
    float* ef     = ws + 12288;         // 50000
    float* er     = ws + 62288;         // 50000
    float* memfun = ws + 112288;        // 2048 ┐
    float* memrul = ws + 114336;        // 2048 ├ zeroed together (4098 floats)
    float* sums   = ws + 116384;        // 2    ┘
    float* ht_ws  = ws + 116392;        // 2048 (16B-aligned)
    float* ha     = ws + 118440;        // 2048
    float* logits = ws + 120488;        // 9

    // 1. zero accumulators (ws is poisoned; atomics accumulate into these)
    k_zero<<<17, 256, 0, stream>>>(memfun, 2 * H + 2);

    // 2. DND exp-sims + keys copies + sums
    k_sims<<<dim3((DICT + 255) / 256, 2), 256, 0, stream>>>(
        f_keys, r_keys, x, ef, er, sums, out + OFF_FK, out + OFF_RK);

    // 3. LSTM preact GEMV
    k_preact<<<HD / 4, 256, 0, stream>>>(W_h2h, W_i2h, b_h2h, b_i2h, h, x, preact);

    // 4. depth-4 flat sweep: vals copy + weighted sums (dominant kernel)
    k_sweep<<<NBLK_SWEEP, 512, 0, stream>>>(
        f_vals, r_vals, ef, er, out + OFF_FV, out + OFF_RV, memfun, memrul);

    // 5. gates -> c_t, h_t (applies 1/sum normalization); h/c outputs + write_idx rows
    k_combine<<<H / 256, 256, 0, stream>>>(preact, c, memfun, memrul, sums, x, widx, out, ht_ws);

    // 6. heads
    k_hidden<<<H / 4, 256, 0, stream>>>(W_ih, b_ih, ht_ws, ha);
    k_heads1<<<9, 256, 0, stream>>>(W_actor, b_actor, W_critic, b_critic, ha, logits);
    k_heads2<<<1, 64, 0, stream>>>(logits, out);
}

// Round 14
// 405.714 us; speedup vs baseline: 1.3088x; 1.3088x over previous
//
#include <hip/hip_runtime.h>
#include <math.h>

#define H        2048
#define HD       12288      // (NG+1)*H
#define DICT     50000
#define FDIM     6
#define RDIM     1
#define IN_DIM   16
#define EPS_F    1e-8f

// d_out flat offsets (floats), in reference return order
#define OFF_PI   ((size_t)0)
#define OFF_V    ((size_t)8)
#define OFF_H    ((size_t)9)
#define OFF_C    ((size_t)2057)
#define OFF_FK   ((size_t)4105)
#define OFF_FV   ((size_t)304105)    // ≡ 1 (mod 4): row-local float j≡3 (mod 4) is 16B-aligned
#define OFF_RK   ((size_t)102704105)
#define OFF_RV   ((size_t)102754105) // ≡ 1 (mod 4), same phase

// megakernel block ranges (round-8 best configuration)
#define R_CHUNK      125                 // vals rows per block
#define NBLK_DICT    (DICT / R_CHUNK)    // 400
#define NBLK_VALS    (2 * NBLK_DICT)     // 800
#define NBLK_PREACT  (HD / 8)            // 1536 (8 rows per 512-thread block)
#define NBLK_TOTAL   (NBLK_VALS + NBLK_PREACT)

typedef float f4v __attribute__((ext_vector_type(4)));

__device__ __forceinline__ float sigf(float v) { return 1.0f / (1.0f + expf(-v)); }

// ---------------- megakernel: vals copy+wsum+sims (blocks 0..799) | preact (800..2335) ----
__global__ __launch_bounds__(512) void k_mega(
    const float* __restrict__ f_keys, const float* __restrict__ r_keys,
    const float* __restrict__ f_vals, const float* __restrict__ r_vals,
    const float* __restrict__ x,
    const float* __restrict__ W_h2h, const float* __restrict__ W_i2h,
    const float* __restrict__ b_h2h, const float* __restrict__ b_i2h,
    const float* __restrict__ h,
    float* __restrict__ out_fv, float* __restrict__ out_rv,
    float* __restrict__ out_fk, float* __restrict__ out_rk,
    float* __restrict__ memfun, float* __restrict__ memrul,
    float* __restrict__ sums, float* __restrict__ preact)
{
    const int b   = blockIdx.x;
    const int tid = threadIdx.x;

    if (b >= NBLK_VALS) {
        // ---- preact: wave per row, 8 rows per block ----
        const int row  = (b - NBLK_VALS) * 8 + (tid >> 6);
        const int lane = tid & 63;
        const float4* Wv = (const float4*)(W_h2h + (size_t)row * H);
        const float4* hv = (const float4*)h;
        float acc = 0.0f;
#pragma unroll
        for (int k = 0; k < 8; ++k) {
            float4 w4 = Wv[lane + (k << 6)];
            float4 h4 = hv[lane + (k << 6)];
            acc += w4.x * h4.x + w4.y * h4.y + w4.z * h4.z + w4.w * h4.w;
        }
        if (lane < IN_DIM) acc += W_i2h[(size_t)row * IN_DIM + lane] * x[lane];
#pragma unroll
        for (int off = 32; off > 0; off >>= 1) acc += __shfl_down(acc, off);
        if (lane == 0) preact[row] = acc + b_h2h[row] + b_i2h[row];
        return;
    }

    // ---- vals blocks ----
    __shared__ float wl[R_CHUNK];
    const int  dict = (b >= NBLK_DICT) ? 1 : 0;
    const int  row0 = (dict ? b - NBLK_DICT : b) * R_CHUNK;

    const float* vals = dict ? r_vals : f_vals;
    float*       outv = dict ? out_rv : out_fv;   // base ≡ 1 (mod 4 floats)
    float*       mem  = dict ? memrul : memfun;

    // fused keys output copy + exp-sims (softmax max-shift unneeded: |sim|<=1)
    if (!dict) {
        for (int i = tid; i < R_CHUNK * FDIM; i += 512)
            out_fk[(size_t)row0 * FDIM + i] = f_keys[(size_t)row0 * FDIM + i];
    } else if (tid < R_CHUNK) {
        out_rk[row0 + tid] = r_keys[row0 + tid];
    }
    if (tid < R_CHUNK) {
        const int row = row0 + tid;
        float e;
        if (!dict) {
            float qn[FDIM]; float qs = 0.0f;
#pragma unroll
            for (int d = 0; d < FDIM; ++d) { float q = x[d]; qn[d] = q; qs += q * q; }
            const float qi = 1.0f / (sqrtf(qs) + EPS_F);
            float ks = 0.0f, dot = 0.0f;
#pragma unroll
            for (int d = 0; d < FDIM; ++d) {
                float kv = f_keys[(size_t)row * FDIM + d];
                ks += kv * kv; dot += kv * qn[d];
            }
            e = expf((dot * qi) / (sqrtf(ks) + EPS_F));
        } else {
            float q  = x[FDIM];
            float kv = r_keys[row];
            e = expf((kv * (q / (fabsf(q) + EPS_F))) / (fabsf(kv) + EPS_F));
        }
        wl[tid] = e;
    }
    __syncthreads();
    if (tid == 0) {
        float s = 0.0f;
        for (int i = 0; i < R_CHUNK; ++i) s += wl[i];
        atomicAdd(&sums[dict], s);
    }

    // ---- streaming copy + weighted sum, BOTH global streams aligned ----
    // Load: thread t loads ALIGNED src quad j=4t..4t+3 (one dwordx4).
    // wsum: thread t owns aligned columns 4t..4t+3 (uniform atomics).
    // Store: thread t<511 stores ALIGNED out quad at 4t+3 = (v.w, next.x/y/z),
    //        neighbor via __shfl_down(.,1); lane 63 reloads neighbor quad (L1-hot).
    //        tid 0 stores edge floats 0,1,2; tid 511 stores edge float 2047.
    // 4-row batches with a barrier per batch: keeps waves lockstep so stores
    // cluster per cacheline (r9: drift => 1.7x write amplification + VGPR blowup);
    // depth 4 keeps 4 loads in flight (r10: depth 1 => store-ack serialization).
    const float* src = vals + (size_t)row0 * 2048;
    float*       dst = outv + (size_t)row0 * 2048;
    const int lane = tid & 63;
    const int j0   = 4 * tid;
    float a0 = 0.f, a1 = 0.f, a2 = 0.f, a3 = 0.f;

    int i = 0;
    for (; i + 4 <= R_CHUNK; i += 4) {
        f4v v0 = *(const f4v*)(src + (size_t)(i    ) * 2048 + j0);
        f4v v1 = *(const f4v*)(src + (size_t)(i + 1) * 2048 + j0);
        f4v v2 = *(const f4v*)(src + (size_t)(i + 2) * 2048 + j0);
        f4v v3 = *(const f4v*)(src + (size_t)(i + 3) * 2048 + j0);
        const float w0 = wl[i], w1 = wl[i + 1], w2 = wl[i + 2], w3 = wl[i + 3];
        a0 += w0 * v0.x + w1 * v1.x + w2 * v2.x + w3 * v3.x;
        a1 += w0 * v0.y + w1 * v1.y + w2 * v2.y + w3 * v3.y;
        a2 += w0 * v0.z + w1 * v1.z + w2 * v2.z + w3 * v3.z;
        a3 += w0 * v0.w + w1 * v1.w + w2 * v2.w + w3 * v3.w;
#pragma unroll
        for (int r = 0; r < 4; ++r) {
            f4v v = (r == 0) ? v0 : (r == 1) ? v1 : (r == 2) ? v2 : v3;
            float nx = __shfl_down(v.x, 1);
            float ny = __shfl_down(v.y, 1);
            float nz = __shfl_down(v.z, 1);
            const float* srow = src + (size_t)(i + r) * 2048;
            float*       drow = dst + (size_t)(i + r) * 2048;
            if (lane == 63 && tid != 511) {
                const float* nq = srow + j0 + 4;
                nx = nq[0]; ny = nq[1]; nz = nq[2];
            }
            if (tid < 511) {
                f4v s; s.x = v.w; s.y = nx; s.z = ny; s.w = nz;
                *(f4v*)(drow + j0 + 3) = s;
            } else {
                drow[2047] = v.w;
            }
            if (tid == 0) { drow[0] = v.x; drow[1] = v.y; drow[2] = v.z; }
        }
        __syncthreads();
    }
    // tail row (125 = 31*4 + 1)
    for (; i < R_CHUNK; ++i) {
        f4v v = *(const f4v*)(src + (size_t)i * 2048 + j0);
        const float w = wl[i];
        a0 += w * v.x; a1 += w * v.y; a2 += w * v.z; a3 += w * v.w;
        float nx = __shfl_down(v.x, 1);
        float ny = __shfl_down(v.y, 1);
        float nz = __shfl_down(v.z, 1);
        const float* srow = src + (size_t)i * 2048;
        float*       drow = dst + (size_t)i * 2048;
        if (lane == 63 && tid != 511) {
            const float* nq = srow + j0 + 4;
            nx = nq[0]; ny = nq[1]; nz = nq[2];
        }
        if (tid < 511) {
            f4v s; s.x = v.w; s.y = nx; s.z = ny; s.w = nz;
            *(f4v*)(drow + j0 + 3) = s;
        } else {
            drow[2047] = v.w;
        }
        if (tid == 0) { drow[0] = v.x; drow[1] = v.y; drow[2] = v.z; }
    }

    atomicAdd(&mem[j0 + 0], a0);
    atomicAdd(&mem[j0 + 1], a1);
    atomicAdd(&mem[j0 + 2], a2);
    atomicAdd(&mem[j0 + 3], a3);
}

// ---------------- gates -> c_t, h_t; write h/c outputs + write_idx rows ----------------
__global__ __launch_bounds__(256) void k_combine(
    const float* __restrict__ preact, const float* __restrict__ c_in,
    const float* __restrict__ memfun, const float* __restrict__ memrul,
    const float* __restrict__ sums,
    const float* __restrict__ x, const int* __restrict__ widx_p,
    float* __restrict__ out, float* __restrict__ ht_ws)
{
    const int j = blockIdx.x * 256 + threadIdx.x;
    if (j >= H) return;
    const int widx = *widx_p;
    const float invf = 1.0f / sums[0];
    const float invr = 1.0f / sums[1];

    float f_t   = sigf(preact[0 * H + j]);
    float i_t   = sigf(preact[1 * H + j]);
    float o_t   = sigf(preact[2 * H + j]);
    float fun_t = sigf(preact[3 * H + j]);
    float rul_t = sigf(preact[4 * H + j]);
    float c_new = tanhf(preact[5 * H + j]);

    float ct = f_t * c_in[j] + i_t * c_new
             + fun_t * tanhf(memfun[j] * invf) + rul_t * tanhf(memrul[j] * invr);
    float ht = o_t * tanhf(ct);

    out[OFF_H + j] = ht;
    out[OFF_C + j] = ct;
    ht_ws[j] = ht;

    out[OFF_FV + (size_t)widx * H + j] = (j < H / 2) ? ct : 0.0f;
    out[OFF_RV + (size_t)widx * H + j] = (j < H / 2) ? 0.0f : ct;
    if (j < FDIM)  out[OFF_FK + (size_t)widx * FDIM + j] = x[j];
    if (j == FDIM) out[OFF_RK + (size_t)widx] = x[FDIM];
}

// ---------------- ha = relu(W_ih @ h_t + b_ih)  (wave per row) ----------------
__global__ __launch_bounds__(256) void k_hidden(
    const float* __restrict__ W_ih, const float* __restrict__ b_ih,
    const float* __restrict__ ht, float* __restrict__ ha)
{
    int gid  = blockIdx.x * blockDim.x + threadIdx.x;
    int row  = gid >> 6;
    int lane = threadIdx.x & 63;
    if (row >= H) return;
    const float4* Wv = (const float4*)(W_ih + (size_t)row * H);
    const float4* hv = (const float4*)ht;
    float acc = 0.0f;
#pragma unroll
    for (int k = 0; k < 8; ++k) {
        float4 w4 = Wv[lane + (k << 6)];
        float4 h4 = hv[lane + (k << 6)];
        acc += w4.x * h4.x + w4.y * h4.y + w4.z * h4.z + w4.w * h4.w;
    }
#pragma unroll
    for (int off = 32; off > 0; off >>= 1) acc += __shfl_down(acc, off);
    if (lane == 0) ha[row] = fmaxf(acc + b_ih[row], 0.0f);
}

// ---------------- heads stage 1: 9 parallel logit GEMVs ----------------
__global__ __launch_bounds__(256) void k_heads1(
    const float* __restrict__ W_actor, const float* __restrict__ b_actor,
    const float* __restrict__ W_critic, const float* __restrict__ b_critic,
    const float* __restrict__ ha, float* __restrict__ logits)
{
    __shared__ float red[4];
    const int o   = blockIdx.x;           // 0..8
    const int tid = threadIdx.x;
    const float* row = (o < 8) ? (W_actor + (size_t)o * H) : W_critic;
    const float4* rv = (const float4*)row;
    const float4* hv = (const float4*)ha;
    float acc = 0.0f;
#pragma unroll
    for (int k = 0; k < 2; ++k) {
        int idx = tid + (k << 8);
        float4 w4 = rv[idx];
        float4 h4 = hv[idx];
        acc += w4.x * h4.x + w4.y * h4.y + w4.z * h4.z + w4.w * h4.w;
    }
#pragma unroll
    for (int off = 32; off > 0; off >>= 1) acc += __shfl_down(acc, off);
    if ((tid & 63) == 0) red[tid >> 6] = acc;
    __syncthreads();
    if (tid == 0)
        logits[o] = red[0] + red[1] + red[2] + red[3] + ((o < 8) ? b_actor[o] : b_critic[0]);
}

// ---------------- heads stage 2: softmax over 8 + critic ----------------
__global__ __launch_bounds__(64) void k_heads2(
    const float* __restrict__ logits, float* __restrict__ out)
{
    if (threadIdx.x == 0) {
        float m = logits[0];
        for (int o = 1; o < 8; ++o) m = fmaxf(m, logits[o]);
        float e[8], s = 0.0f;
        for (int o = 0; o < 8; ++o) { e[o] = expf(logits[o] - m); s += e[o]; }
        for (int o = 0; o < 8; ++o) out[OFF_PI + o] = e[o] / s;
        out[OFF_V] = logits[8];
    }
}

extern "C" void kernel_launch(void* const* d_in, const int* in_sizes, int n_in,
                              void* d_out, int out_size, void* d_ws, size_t ws_size,
                              hipStream_t stream)
{
    const float* x        = (const float*)d_in[0];
    const float* h        = (const float*)d_in[1];
    const float* c        = (const float*)d_in[2];
    const float* W_i2h    = (const float*)d_in[3];
    const float* b_i2h    = (const float*)d_in[4];
    const float* W_h2h    = (const float*)d_in[5];
    const float* b_h2h    = (const float*)d_in[6];
    const float* f_keys   = (const float*)d_in[7];
    const float* f_vals   = (const float*)d_in[8];
    const float* r_keys   = (const float*)d_in[9];
    const float* r_vals   = (const float*)d_in[10];
    const float* W_ih     = (const float*)d_in[11];
    const float* b_ih     = (const float*)d_in[12];
    const float* W_actor  = (const float*)d_in[13];
    const float* b_actor  = (const float*)d_in[14];
    const float* W_critic = (const float*)d_in[15];
    const float* b_critic = (const float*)d_in[16];
    const int*   widx     = (const int*)d_in[17];

    float* out = (float*)d_out;
    float* ws  = (float*)d_ws;

    // ws layout (floats)
    float* preact = ws;                 // 12288
    float* memfun = ws + 12288;         // 2048 ┐
    float* memrul = ws + 14336;         // 2048 ├ zeroed together (4098 floats)
    float* sums   = ws + 16384;         // 2    ┘
    float* ht_ws  = ws + 16388;         // 2048 (16B-aligned)
    float* ha     = ws + 18436;         // 2048 (16B-aligned)
    float* logits = ws + 20484;         // 9

    // 1. zero accumulators (0.0f == all-zero bytes; memset is graph-capture-safe)
    hipMemsetAsync(memfun, 0, (2 * H + 2) * sizeof(float), stream);

    // 2. megakernel: vals copy+wsum+sims+keys (blocks 0..799) | preact (800..2335)
    k_mega<<<NBLK_TOTAL, 512, 0, stream>>>(
        f_keys, r_keys, f_vals, r_vals, x,
        W_h2h, W_i2h, b_h2h, b_i2h, h,
        out + OFF_FV, out + OFF_RV, out + OFF_FK, out + OFF_RK,
        memfun, memrul, sums, preact);

    // 3. gates -> c_t, h_t (applies 1/sum normalization); h/c outputs + write_idx rows
    k_combine<<<H / 256, 256, 0, stream>>>(preact, c, memfun, memrul, sums, x, widx, out, ht_ws);

    // 4. heads
    k_hidden<<<H / 4, 256, 0, stream>>>(W_ih, b_ih, ht_ws, ha);
    k_heads1<<<9, 256, 0, stream>>>(W_actor, b_actor, W_critic, b_critic, ha, logits);
    k_heads2<<<1, 64, 0, stream>>>(logits, out);
}